// Round 6
// baseline (4166.907 us; speedup 1.0000x reference)
//
#include <hip/hip_runtime.h>
#include <hip/hip_bf16.h>
#include <cstdint>
#include <cstddef>

typedef __bf16 bf16;
typedef bf16 bf16x8 __attribute__((ext_vector_type(8)));
typedef float f32x4 __attribute__((ext_vector_type(4)));

#define D_DIM 128
#define EB 32      // rows (edges or nodes) per block
#define TS 136     // LDS stride for 128-wide tiles (+8 pad: 16B-aligned, 2-way bank alias = free)
#define XS 264     // LDS stride for 256-wide x2 tile
#define AS 392     // LDS stride for 384-wide node-A input tile

__device__ __forceinline__ f32x4 mfma16(bf16x8 a, bf16x8 b, f32x4 c) {
  return __builtin_amdgcn_mfma_f32_16x16x32_bf16(a, b, c, 0, 0, 0);
}

__device__ __forceinline__ int clampi(int v, int hi) {
  return v < 0 ? 0 : (v > hi ? hi : v);
}

// stage 16 consecutive f32 (64B, aligned) -> 16 bf16 in LDS
__device__ __forceinline__ void stage16(const float* __restrict__ src, bf16* dst) {
  bf16 tmp[16];
#pragma unroll
  for (int q = 0; q < 4; ++q) {
    f32x4 f = ((const f32x4*)src)[q];
#pragma unroll
    for (int j = 0; j < 4; ++j) tmp[q * 4 + j] = (bf16)f[j];
  }
  *(bf16x8*)dst = *(bf16x8*)tmp;
  *(bf16x8*)(dst + 8) = *(bf16x8*)(tmp + 8);
}

// ---- layer1: A[32 x K] (K = NSEG*128, from LDS segments) @ W1t[256 x K]^T, relu(+b1) -> x2[32 x 256] bf16
template <int NSEG>
__device__ __forceinline__ void mlp_layer1(const bf16* s0, const bf16* s1, const bf16* s2,
                                           const int S,
                                           const bf16* __restrict__ W1t,
                                           const float* __restrict__ B1,
                                           bf16* x2, const int lane, const int w) {
  const int col = lane & 15, quad = lane >> 4;
  const int K = NSEG * 128;
  f32x4 acc[2][4] = {};
  const bf16* segs[3] = {s0, s1, s2};
#pragma unroll
  for (int sg = 0; sg < NSEG; ++sg) {
    const bf16* xl = segs[sg];
#pragma unroll
    for (int kk = 0; kk < 128; kk += 32) {
      const int k0 = sg * 128 + kk;
      bf16x8 a0 = *(const bf16x8*)&xl[col * S + kk + quad * 8];
      bf16x8 a1 = *(const bf16x8*)&xl[(col + 16) * S + kk + quad * 8];
#pragma unroll
      for (int nt = 0; nt < 4; ++nt) {
        bf16x8 b = *(const bf16x8*)(W1t + (size_t)(w * 64 + nt * 16 + col) * K + k0 + quad * 8);
        acc[0][nt] = mfma16(a0, b, acc[0][nt]);
        acc[1][nt] = mfma16(a1, b, acc[1][nt]);
      }
    }
  }
#pragma unroll
  for (int nt = 0; nt < 4; ++nt) {
    const int n = w * 64 + nt * 16 + col;
    const float b1 = B1[n];
#pragma unroll
    for (int mt = 0; mt < 2; ++mt)
#pragma unroll
      for (int i = 0; i < 4; ++i) {
        float v = acc[mt][nt][i] + b1;
        x2[(mt * 16 + quad * 4 + i) * XS + n] = (bf16)(v > 0.f ? v : 0.f);
      }
  }
}

// ---- layer2: x2[32 x 256] @ W2t[128 x 256]^T -> acc2 (no bias/act; caller epilogue)
__device__ __forceinline__ void mlp_layer2(const bf16* x2, const bf16* __restrict__ W2t,
                                           const int lane, const int w, f32x4 acc2[2][2]) {
  const int col = lane & 15, quad = lane >> 4;
#pragma unroll
  for (int k0 = 0; k0 < 256; k0 += 32) {
    bf16x8 a0 = *(const bf16x8*)&x2[col * XS + k0 + quad * 8];
    bf16x8 a1 = *(const bf16x8*)&x2[(col + 16) * XS + k0 + quad * 8];
#pragma unroll
    for (int nt = 0; nt < 2; ++nt) {
      bf16x8 b = *(const bf16x8*)(W2t + (size_t)(w * 32 + nt * 16 + col) * 256 + k0 + quad * 8);
      acc2[0][nt] = mfma16(a0, b, acc2[0][nt]);
      acc2[1][nt] = mfma16(a1, b, acc2[1][nt]);
    }
  }
}

// ---------------- small utility kernels ----------------

// f32 [K,N] -> bf16 [N,K]
__global__ void transpose_kernel(const float* __restrict__ in, bf16* __restrict__ out,
                                 int K, int N) {
  int k = blockIdx.x * blockDim.x + threadIdx.x;
  int n = blockIdx.y;
  if (k < K) out[(size_t)n * K + k] = (bf16)in[(size_t)k * N + n];
}

__global__ void count_kernel(const int* __restrict__ epn, const int* __restrict__ ecn,
                             int* cntp, int* cntc, int E, int N) {
  int i = blockIdx.x * blockDim.x + threadIdx.x;
  if (i < E) {
    atomicAdd(&cntp[clampi(epn[i], N - 1)], 1);
    atomicAdd(&cntc[clampi(ecn[i], N - 1)], 1);
  }
}

__global__ void inv_kernel(const int* __restrict__ cntp, const int* __restrict__ cntc,
                           float* invp, float* invc, int N) {
  int i = blockIdx.x * blockDim.x + threadIdx.x;
  if (i < N) {
    invp[i] = 1.f / fmaxf((float)cntp[i], 1.f);
    invc[i] = 1.f / fmaxf((float)cntc[i], 1.f);
  }
}

// ---------------- MLP_V: h = mlp(batch_token), h stored f32 ----------------

__global__ __launch_bounds__(256, 2) void node_v_kernel(
    const float* __restrict__ bt, const bf16* __restrict__ W1t, const float* __restrict__ B1,
    const bf16* __restrict__ W2t, const float* __restrict__ B2, float* __restrict__ hout, int N) {
  __shared__ __attribute__((aligned(16))) bf16 x[EB * TS];
  __shared__ __attribute__((aligned(16))) bf16 x2[EB * XS];
  const int t = threadIdx.x;
  const int r0 = blockIdx.x * EB;
  {
    const int r = t >> 3, c0 = (t & 7) * 16;  // 32 rows x 8 threads x 16 f32 = 128 cols
    int g = r0 + r; if (g >= N) g = N - 1;
    stage16(bt + (size_t)g * D_DIM + c0, &x[r * TS + c0]);
  }
  __syncthreads();
  const int lane = t & 63, w = t >> 6, col = lane & 15, quad = lane >> 4;
  mlp_layer1<1>(x, x, x, TS, W1t, B1, x2, lane, w);
  __syncthreads();
  f32x4 acc2[2][2] = {};
  mlp_layer2(x2, W2t, lane, w, acc2);
#pragma unroll
  for (int nt = 0; nt < 2; ++nt) {
    const int n = w * 32 + nt * 16 + col;
    const float b2 = B2[n];
#pragma unroll
    for (int mt = 0; mt < 2; ++mt)
#pragma unroll
      for (int i = 0; i < 4; ++i) {
        int m = mt * 16 + quad * 4 + i;
        int g = r0 + m;
        if (g < N) {
          float v = acc2[mt][nt][i] + b2;
          hout[(size_t)g * D_DIM + n] = v > 0.f ? v : 0.f;
        }
      }
  }
}

// ---------------- per-hop edge kernel: inline edge feats + MLP_P + MLP_C + atomic scatter ----

__global__ __launch_bounds__(256, 2) void edge_hop_kernel(
    const float* __restrict__ h,
    const float* __restrict__ epi, const float* __restrict__ eci,
    const int* __restrict__ epn, const int* __restrict__ ecn,
    const float* __restrict__ Ew1, const float* __restrict__ Eb1,
    const bf16* __restrict__ Ew2t, const float* __restrict__ Eb2,
    const bf16* __restrict__ Pw1t, const float* __restrict__ Pb1,
    const bf16* __restrict__ Pw2t, const float* __restrict__ Pb2,
    const bf16* __restrict__ Cw1t, const float* __restrict__ Cb1,
    const bf16* __restrict__ Cw2t, const float* __restrict__ Cb2,
    float* __restrict__ accp, float* __restrict__ accc, int E, int N) {
  __shared__ int s_ip[EB], s_ic[EB];
  __shared__ float s_xp[EB], s_xc[EB];
  __shared__ __attribute__((aligned(16))) bf16 tiles[4 * EB * TS];  // hc, hp, ep, ec
  __shared__ __attribute__((aligned(16))) bf16 x2[EB * XS];
  const int t = threadIdx.x;
  const int e0 = blockIdx.x * EB;
  if (t < EB) {
    int e = e0 + t; if (e >= E) e = E - 1;
    s_ip[t] = clampi(epn[e], N - 1);
    s_xp[t] = epi[e];
  } else if (t < 2 * EB) {
    int e = e0 + t - EB; if (e >= E) e = E - 1;
    s_ic[t - EB] = clampi(ecn[e], N - 1);
    s_xc[t - EB] = eci[e];
  }
  __syncthreads();
  // gather h rows (f32 -> bf16), full 128-col width
  {
    const int r = t >> 3, c0 = (t & 7) * 16;
    stage16(h + (size_t)s_ic[r] * D_DIM + c0, &tiles[0 * EB * TS + r * TS + c0]);  // hc
    stage16(h + (size_t)s_ip[r] * D_DIM + c0, &tiles[1 * EB * TS + r * TS + c0]);  // hp
  }
  const int lane = t & 63, w = t >> 6, col = lane & 15, quad = lane >> 4;

  // inline edge features: ep -> tiles[2], ec -> tiles[3]
  const float ew1 = Ew1[t];   // layer1 col n = t (256 cols)
  const float eb1 = Eb1[t];
#pragma unroll
  for (int f = 0; f < 2; ++f) {
    const float* sx = f ? s_xc : s_xp;
    bf16* dst = &tiles[(2 + f) * EB * TS];
#pragma unroll 4
    for (int m = 0; m < EB; ++m) {
      float v = sx[m] * ew1 + eb1;
      x2[m * XS + t] = (bf16)(v > 0.f ? v : 0.f);
    }
    __syncthreads();   // also covers the h-gather on the first iteration
    f32x4 acc2[2][2] = {};
    mlp_layer2(x2, Ew2t, lane, w, acc2);
#pragma unroll
    for (int nt = 0; nt < 2; ++nt) {
      const int n = w * 32 + nt * 16 + col;
      const float b2 = Eb2[n];
#pragma unroll
      for (int mt = 0; mt < 2; ++mt)
#pragma unroll
        for (int i = 0; i < 4; ++i) {
          int m = mt * 16 + quad * 4 + i;
          float v = acc2[mt][nt][i] + b2;
          dst[m * TS + n] = (bf16)(v > 0.f ? v : 0.f);
        }
    }
    __syncthreads();  // x2 free for next feature / P-MLP
  }

  auto run_mlp = [&](const bf16* g0, const bf16* g1, const bf16* g2,
                     const bf16* W1t, const float* B1, const bf16* W2t, const float* B2,
                     float* outacc, const int* sidx) {
    mlp_layer1<3>(g0, g1, g2, TS, W1t, B1, x2, lane, w);
    __syncthreads();
    f32x4 acc2[2][2] = {};
    mlp_layer2(x2, W2t, lane, w, acc2);
#pragma unroll
    for (int nt = 0; nt < 2; ++nt) {
      const int n = w * 32 + nt * 16 + col;
      const float b2 = B2[n];
#pragma unroll
      for (int mt = 0; mt < 2; ++mt)
#pragma unroll
        for (int i = 0; i < 4; ++i) {
          int m = mt * 16 + quad * 4 + i;
          if (e0 + m < E) {
            float v = acc2[mt][nt][i] + b2;
            v = v > 0.f ? v : 0.f;
            __hip_atomic_fetch_add(&outacc[(size_t)sidx[m] * D_DIM + n], v,
                                   __ATOMIC_RELAXED, __HIP_MEMORY_SCOPE_AGENT);
          }
        }
    }
    __syncthreads();  // protect x2 before reuse / next call
  };
  const bf16* thc = &tiles[0 * EB * TS];
  const bf16* thp = &tiles[1 * EB * TS];
  const bf16* tep = &tiles[2 * EB * TS];
  const bf16* tec = &tiles[3 * EB * TS];
  run_mlp(thc, thp, tep, Pw1t, Pb1, Pw2t, Pb2, accp, s_ip);  // s_p = mlp([hc,hp,ep])
  run_mlp(thp, thc, tec, Cw1t, Cb1, Cw2t, Cb2, accc, s_ic);  // s_c = mlp([hp,hc,ec])
}

// ---------------- per-hop node kernel: MLP_A + residual (h f32 in/out) ----------------

__global__ __launch_bounds__(256, 2) void node_a_kernel(
    const float* __restrict__ h, const float* __restrict__ accp, const float* __restrict__ accc,
    const float* __restrict__ invp, const float* __restrict__ invc,
    const float* __restrict__ pmask, const float* __restrict__ cmask,
    const float* __restrict__ stok, const float* __restrict__ etok,
    const bf16* __restrict__ W1t, const float* __restrict__ B1,
    const bf16* __restrict__ W2t, const float* __restrict__ B2,
    float* __restrict__ hout, int N) {
  __shared__ __attribute__((aligned(16))) bf16 x[EB * AS];  // [h | s_p | s_c]
  __shared__ __attribute__((aligned(16))) bf16 x2[EB * XS];
  const int t = threadIdx.x;
  const int r0 = blockIdx.x * EB;
  {
    // stage h (f32 -> bf16) into cols 0..127
    const int r = t >> 3, c0 = (t & 7) * 16;
    int g = r0 + r; if (g >= N) g = N - 1;
    stage16(h + (size_t)g * D_DIM + c0, &x[r * AS + c0]);
  }
  {
    const int j = t;  // 0..255: cols 128..383 ; wave-uniform branch
    for (int r = 0; r < EB; ++r) {
      int g = r0 + r; if (g >= N) g = N - 1;
      float v;
      if (j < 128)
        v = accp[(size_t)g * D_DIM + j] * invp[g] + pmask[g] * stok[j];
      else {
        int jj = j - 128;
        v = accc[(size_t)g * D_DIM + jj] * invc[g] + cmask[g] * etok[jj];
      }
      x[r * AS + 128 + j] = (bf16)v;
    }
  }
  __syncthreads();
  const int lane = t & 63, w = t >> 6, col = lane & 15, quad = lane >> 4;
  mlp_layer1<3>(x, x + 128, x + 256, AS, W1t, B1, x2, lane, w);
  __syncthreads();
  f32x4 acc2[2][2] = {};
  mlp_layer2(x2, W2t, lane, w, acc2);
#pragma unroll
  for (int nt = 0; nt < 2; ++nt) {
    const int n = w * 32 + nt * 16 + col;
    const float b2 = B2[n];
#pragma unroll
    for (int mt = 0; mt < 2; ++mt)
#pragma unroll
      for (int i = 0; i < 4; ++i) {
        int m = mt * 16 + quad * 4 + i;
        int g = r0 + m;
        if (g < N) {
          float mlpv = acc2[mt][nt][i] + b2;
          mlpv = mlpv > 0.f ? mlpv : 0.f;
          float hold = h[(size_t)g * D_DIM + n];  // exact f32 residual
          float v = hold + mlpv;
          hout[(size_t)g * D_DIM + n] = v > 0.f ? v : 0.f;
        }
      }
  }
}

// ---------------- host launch ----------------

extern "C" void kernel_launch(void* const* d_in, const int* in_sizes, int n_in,
                              void* d_out, int out_size, void* d_ws, size_t ws_size,
                              hipStream_t stream) {
  const float* batch_token = (const float*)d_in[0];
  const int* epn = (const int*)d_in[1];
  const int* ecn = (const int*)d_in[2];
  const float* epi = (const float*)d_in[3];
  const float* eci = (const float*)d_in[4];
  const float* pmask = (const float*)d_in[5];
  const float* cmask = (const float*)d_in[6];
  const float* stok = (const float*)d_in[7];
  const float* etok = (const float*)d_in[8];
  const float *Vw1 = (const float*)d_in[9], *Vb1 = (const float*)d_in[10],
              *Vw2 = (const float*)d_in[11], *Vb2 = (const float*)d_in[12];
  const float *Ew1 = (const float*)d_in[13], *Eb1 = (const float*)d_in[14],
              *Ew2 = (const float*)d_in[15], *Eb2 = (const float*)d_in[16];
  const float *Pw1 = (const float*)d_in[17], *Pb1 = (const float*)d_in[18],
              *Pw2 = (const float*)d_in[19], *Pb2 = (const float*)d_in[20];
  const float *Cw1 = (const float*)d_in[21], *Cb1 = (const float*)d_in[22],
              *Cw2 = (const float*)d_in[23], *Cb2 = (const float*)d_in[24];
  const float *Aw1 = (const float*)d_in[25], *Ab1 = (const float*)d_in[26],
              *Aw2 = (const float*)d_in[27], *Ab2 = (const float*)d_in[28];
  const int N = in_sizes[5];  // p_mask length
  const int E = in_sizes[1];  // edge_p_node length

  char* ws = (char*)d_ws;
  size_t off = 0;
  auto alloc = [&](size_t bytes) {
    size_t o = off;
    off += (bytes + 511) & ~(size_t)511;
    return o;
  };
  float* accp = (float*)(ws + alloc((size_t)N * D_DIM * 4));
  float* accc = (float*)(ws + alloc((size_t)N * D_DIM * 4));
  float* invp = (float*)(ws + alloc((size_t)N * 4));
  float* invc = (float*)(ws + alloc((size_t)N * 4));
  int* cntp = (int*)(ws + alloc((size_t)N * 4));
  int* cntc = (int*)(ws + alloc((size_t)N * 4));
  bf16* Vw1t = (bf16*)(ws + alloc(128 * 256 * 2));
  bf16* Pw1t = (bf16*)(ws + alloc(384 * 256 * 2));
  bf16* Cw1t = (bf16*)(ws + alloc(384 * 256 * 2));
  bf16* Aw1t = (bf16*)(ws + alloc(384 * 256 * 2));
  bf16* Vw2t = (bf16*)(ws + alloc(256 * 128 * 2));
  bf16* Ew2t = (bf16*)(ws + alloc(256 * 128 * 2));
  bf16* Pw2t = (bf16*)(ws + alloc(256 * 128 * 2));
  bf16* Cw2t = (bf16*)(ws + alloc(256 * 128 * 2));
  bf16* Aw2t = (bf16*)(ws + alloc(256 * 128 * 2));
  float* hbuf = (float*)d_out;  // h lives in d_out across hops as FLOAT32 (output dtype)
  (void)ws_size; (void)n_in; (void)out_size;

  const dim3 blk(256);
  // weight transposes (f32 -> bf16): out[n*K+k] = in[k*N+n]
  transpose_kernel<<<dim3(1, 256), blk, 0, stream>>>(Vw1, Vw1t, 128, 256);
  transpose_kernel<<<dim3(2, 256), blk, 0, stream>>>(Pw1, Pw1t, 384, 256);
  transpose_kernel<<<dim3(2, 256), blk, 0, stream>>>(Cw1, Cw1t, 384, 256);
  transpose_kernel<<<dim3(2, 256), blk, 0, stream>>>(Aw1, Aw1t, 384, 256);
  transpose_kernel<<<dim3(1, 128), blk, 0, stream>>>(Vw2, Vw2t, 256, 128);
  transpose_kernel<<<dim3(1, 128), blk, 0, stream>>>(Ew2, Ew2t, 256, 128);
  transpose_kernel<<<dim3(1, 128), blk, 0, stream>>>(Pw2, Pw2t, 256, 128);
  transpose_kernel<<<dim3(1, 128), blk, 0, stream>>>(Cw2, Cw2t, 256, 128);
  transpose_kernel<<<dim3(1, 128), blk, 0, stream>>>(Aw2, Aw2t, 256, 128);

  // degree counts -> reciprocals
  const size_t cntbytes = (size_t)((char*)(cntc + N) - (char*)cntp);
  hipMemsetAsync(cntp, 0, cntbytes, stream);
  count_kernel<<<dim3((E + 255) / 256), blk, 0, stream>>>(epn, ecn, cntp, cntc, E, N);
  inv_kernel<<<dim3((N + 255) / 256), blk, 0, stream>>>(cntp, cntc, invp, invc, N);

  const int nblocks = (N + EB - 1) / EB;
  const int eblocks = (E + EB - 1) / EB;

  // h = MLP_V(batch_token)  (f32 into d_out)
  node_v_kernel<<<dim3(nblocks), blk, 0, stream>>>(batch_token, Vw1t, Vb1, Vw2t, Vb2, hbuf, N);

  const size_t accbytes = (size_t)((char*)(accc + (size_t)N * D_DIM) - (char*)accp);
  for (int hop = 0; hop < 3; ++hop) {
    hipMemsetAsync(accp, 0, accbytes, stream);
    edge_hop_kernel<<<dim3(eblocks), blk, 0, stream>>>(
        hbuf, epi, eci, epn, ecn, Ew1, Eb1, Ew2t, Eb2,
        Pw1t, Pb1, Pw2t, Pb2, Cw1t, Cb1, Cw2t, Cb2, accp, accc, E, N);
    node_a_kernel<<<dim3(nblocks), blk, 0, stream>>>(
        hbuf, accp, accc, invp, invc, pmask, cmask, stok, etok, Aw1t, Ab1, Aw2t, Ab2, hbuf, N);
  }
}